// Round 8
// baseline (271.090 us; speedup 1.0000x reference)
//
#include <hip/hip_runtime.h>
#include <math.h>

// ---------------------------------------------------------------------------
// Pipeline v4 — two-level dst sort + CSR-vector (16 lanes/node) aggregation.
//   k_bucket : radix pass 1 (dst>>10): LDS counting sort per 16k chunk,
//              coalesced run write-out. Wave-shuffle hierarchical scan.
//   k_sort   : radix pass 2 (dst&1023) per bucket; rank atomic doubles as
//              degree histogram; in-place coalesced write-back of sorted
//              src; CSR start[]; fused dinv/u epilogue. Shuffle scan.
//   k_agg1   : atomic-free. 16-lane group per node: coalesced segment read,
//              gather u, shfl-reduce; MLP epilogue compacted to one wave.
//   k_agg2   : same walk on q; log_softmax epilogue compacted.
// Round-7 analysis: CSR-scalar walk cost ~2x mean (wave waits on max-degree
// lane, E[max of 64 Poisson(16)] ~ 33) and file reads were uncoalesced.
// ---------------------------------------------------------------------------

typedef unsigned int uint4v __attribute__((ext_vector_type(4)));

#define NPB 1024            // nodes per bucket
#define NPB_SHIFT 10
#define NPB_MASK (NPB - 1)
#define MAXB 512            // max buckets
#define P1T 512             // k_bucket threads
#define CHUNK 16384         // edges per k_bucket block
#define SORT_CAP 17408      // per-bucket file capacity
#define SPT 17              // SORT_CAP / 1024 entries per k_sort thread
#define AGG_T 1024          // agg block threads
#define LPN 16              // lanes per node
#define NPBK (AGG_T / LPN)  // nodes per agg block = 64

__device__ __forceinline__ unsigned short f2bf(float f) {
    unsigned int x = __float_as_uint(f);
    x += 0x7fffu + ((x >> 16) & 1u);            // round-to-nearest-even
    return (unsigned short)(x >> 16);
}
__device__ __forceinline__ float bf2f(unsigned short h) {
    return __uint_as_float((unsigned int)h << 16);
}

// ---------------------------------------------------------------------------
// Phase 1: bucket by dst>>10, coalesced per-wave run write-out.
// ---------------------------------------------------------------------------
__global__ __launch_bounds__(P1T, 4) void k_bucket(
    const int* __restrict__ src, const int* __restrict__ dst,
    unsigned int* __restrict__ file, int* __restrict__ ctr,
    int E, int nbucket, int cap)
{
    __shared__ unsigned int sorted[CHUNK];   // 64 KB
    __shared__ int cnt[MAXB];
    __shared__ int pre[MAXB + 1];
    __shared__ int gb[MAXB];
    __shared__ int rk[MAXB];
    __shared__ int wsum[P1T / 64];

    const int t  = threadIdx.x;
    const int e0 = blockIdx.x * CHUNK;
    const int nE = min(CHUNK, E - e0);

    for (int b = t; b < MAXB; b += P1T) { cnt[b] = 0; rk[b] = 0; }
    __syncthreads();

    const bool full = (nE == CHUNK);
    int4 dc[8];

    if (full) {
        const int4* d4 = (const int4*)(dst + e0);
#pragma unroll
        for (int k = 0; k < 8; ++k) dc[k] = d4[t + k * P1T];
#pragma unroll
        for (int k = 0; k < 8; ++k) {
            atomicAdd(&cnt[((unsigned)dc[k].x) >> NPB_SHIFT], 1);
            atomicAdd(&cnt[((unsigned)dc[k].y) >> NPB_SHIFT], 1);
            atomicAdd(&cnt[((unsigned)dc[k].z) >> NPB_SHIFT], 1);
            atomicAdd(&cnt[((unsigned)dc[k].w) >> NPB_SHIFT], 1);
        }
    } else {
        for (int i = t; i < nE; i += P1T)
            atomicAdd(&cnt[((unsigned)dst[e0 + i]) >> NPB_SHIFT], 1);
    }
    __syncthreads();

    // hierarchical inclusive scan (wave shfl + wave-sum scan): 3 barriers
    {
        const int lane = t & 63, wv = t >> 6;
        int v = (t < nbucket) ? cnt[t] : 0;
#pragma unroll
        for (int d = 1; d < 64; d <<= 1) {
            int nv = __shfl_up(v, d, 64);
            if (lane >= d) v += nv;
        }
        if (lane == 63) wsum[wv] = v;
        __syncthreads();
        if (t < P1T / 64) {
            int s = wsum[t];
#pragma unroll
            for (int d = 1; d < P1T / 64; d <<= 1) {
                int ns = __shfl_up(s, d, P1T / 64);
                if (t >= d) s += ns;
            }
            wsum[t] = s;
        }
        __syncthreads();
        pre[t + 1] = (wv ? wsum[wv - 1] : 0) + v;
        if (t == 0) pre[0] = 0;
    }
    __syncthreads();

    for (int b = t; b < nbucket; b += P1T) {
        int c = cnt[b];
        gb[b] = c ? atomicAdd(&ctr[b], c) : 0;
    }
    __syncthreads();

    if (full) {
        const int4* s4 = (const int4*)(src + e0);
#pragma unroll
        for (int k = 0; k < 8; ++k) {
            int4 s = s4[t + k * P1T];
            int4 d = dc[k];
            {
                int b = ((unsigned)d.x) >> NPB_SHIFT;
                int r = atomicAdd(&rk[b], 1);
                sorted[pre[b] + r] = (((unsigned)s.x) << NPB_SHIFT) | ((unsigned)d.x & NPB_MASK);
            }
            {
                int b = ((unsigned)d.y) >> NPB_SHIFT;
                int r = atomicAdd(&rk[b], 1);
                sorted[pre[b] + r] = (((unsigned)s.y) << NPB_SHIFT) | ((unsigned)d.y & NPB_MASK);
            }
            {
                int b = ((unsigned)d.z) >> NPB_SHIFT;
                int r = atomicAdd(&rk[b], 1);
                sorted[pre[b] + r] = (((unsigned)s.z) << NPB_SHIFT) | ((unsigned)d.z & NPB_MASK);
            }
            {
                int b = ((unsigned)d.w) >> NPB_SHIFT;
                int r = atomicAdd(&rk[b], 1);
                sorted[pre[b] + r] = (((unsigned)s.w) << NPB_SHIFT) | ((unsigned)d.w & NPB_MASK);
            }
        }
    } else {
        for (int i = t; i < nE; i += P1T) {
            int d = dst[e0 + i];
            int b = ((unsigned)d) >> NPB_SHIFT;
            unsigned int w = (((unsigned)src[e0 + i]) << NPB_SHIFT) |
                             ((unsigned)d & NPB_MASK);
            int r = atomicAdd(&rk[b], 1);
            sorted[pre[b] + r] = w;
        }
    }
    __syncthreads();

    {   // per-wave run write-out, clamped to cap
        const int wid  = t >> 6;
        const int lane = t & 63;
        const int nw   = P1T >> 6;
        for (int b = wid; b < nbucket; b += nw) {
            int s0 = pre[b], s1 = pre[b + 1];
            int base = gb[b];
            unsigned int* dp = file + (size_t)b * cap;
            for (int j = s0 + lane; j < s1; j += 64) {
                int idx = base + (j - s0);
                if (idx < cap)
                    __builtin_nontemporal_store(sorted[j], &dp[idx]);
            }
        }
    }
}

// ---------------------------------------------------------------------------
// Phase 2: per-bucket sort by dstlo; rank atomic == degree histogram.
// ---------------------------------------------------------------------------
__global__ __launch_bounds__(NPB) void k_sort(
    unsigned int* __restrict__ file, const int* __restrict__ ctr,
    int* __restrict__ start, const float* __restrict__ x,
    float* __restrict__ dinv, unsigned short* __restrict__ u,
    int N, int cap)
{
    __shared__ unsigned int sorted[SORT_CAP];  // 69.6 KB
    __shared__ int cnt[NPB];
    __shared__ int pre[NPB + 1];
    __shared__ int wsum[NPB / 64];

    const int t = threadIdx.x;
    const int b = blockIdx.x;
    const int nb = min(ctr[b], cap);
    unsigned int* f = file + (size_t)b * cap;

    cnt[t] = 0;
    __syncthreads();

    unsigned int ev[SPT];
    int rk_[SPT];
#pragma unroll
    for (int k = 0; k < SPT; ++k) {
        int i = t + (k << NPB_SHIFT);
        if (i < nb) ev[k] = __builtin_nontemporal_load(f + i);
    }
#pragma unroll
    for (int k = 0; k < SPT; ++k) {
        int i = t + (k << NPB_SHIFT);
        if (i < nb) rk_[k] = atomicAdd(&cnt[ev[k] & NPB_MASK], 1);
    }
    __syncthreads();

    // hierarchical inclusive scan of cnt -> pre (3 barriers)
    {
        const int lane = t & 63, wv = t >> 6;
        int v = cnt[t];
#pragma unroll
        for (int d = 1; d < 64; d <<= 1) {
            int nv = __shfl_up(v, d, 64);
            if (lane >= d) v += nv;
        }
        if (lane == 63) wsum[wv] = v;
        __syncthreads();
        if (t < NPB / 64) {
            int s = wsum[t];
#pragma unroll
            for (int d = 1; d < NPB / 64; d <<= 1) {
                int ns = __shfl_up(s, d, NPB / 64);
                if (t >= d) s += ns;
            }
            wsum[t] = s;
        }
        __syncthreads();
        pre[t + 1] = (wv ? wsum[wv - 1] : 0) + v;
        if (t == 0) pre[0] = 0;
    }
    __syncthreads();

    // scatter src into dst-sorted LDS order
#pragma unroll
    for (int k = 0; k < SPT; ++k) {
        int i = t + (k << NPB_SHIFT);
        if (i < nb)
            sorted[pre[ev[k] & NPB_MASK] + rk_[k]] = ev[k] >> NPB_SHIFT;
    }
    __syncthreads();

    // coalesced in-place write-back
    for (int i = t; i < nb; i += NPB)
        __builtin_nontemporal_store(sorted[i], &f[i]);

    // CSR offsets
    start[b * (NPB + 1) + t] = pre[t];
    if (t == 0) start[b * (NPB + 1) + NPB] = pre[NPB];

    // node epilogue
    const int g = b * NPB + t;
    if (g < N) {
        float dv = rsqrtf((float)(cnt[t] + 1));   // +1 self-loop
        dinv[g] = dv;
        u[g] = f2bf(x[g] * dv);
    }
}

// ---------------------------------------------------------------------------
// Phase 3: CSR-vector agg1. 16 lanes/node; MLP compacted to one wave.
// ---------------------------------------------------------------------------
__global__ __launch_bounds__(AGG_T) void k_agg1(
    const unsigned int* __restrict__ file, const int* __restrict__ start,
    const unsigned short* __restrict__ u, const float* __restrict__ dinv,
    const float* __restrict__ W1, const float* __restrict__ b1,
    const float* __restrict__ W2, unsigned int* __restrict__ q,
    int N, int cap)
{
    __shared__ float sacc[NPBK];
    const int t = threadIdx.x;
    const int grp = t >> 4;
    const int sl  = t & (LPN - 1);
    const int g = blockIdx.x * NPBK + grp;

    float acc = 0.f;
    if (g < N) {
        int b = g >> NPB_SHIFT, loc = g & NPB_MASK;
        const int* st = start + b * (NPB + 1);
        int e0 = st[loc], e1 = st[loc + 1];
        const unsigned int* f = file + (size_t)b * cap;
        for (int j = e0 + sl; j < e1; j += LPN)
            acc += bf2f(u[__builtin_nontemporal_load(f + j)]);
    }
#pragma unroll
    for (int d = LPN / 2; d; d >>= 1) acc += __shfl_down(acc, d, LPN);
    if (sl == 0) sacc[grp] = acc;
    __syncthreads();

    if (t < NPBK) {
        int g2 = blockIdx.x * NPBK + t;
        if (g2 < N) {
            float dv = dinv[g2];
            float s1v = (sacc[t] + bf2f(u[g2])) * dv;
            float c0 = 0.f, c1 = 0.f;
#pragma unroll
            for (int k = 0; k < 16; ++k) {
                float h = fmaxf(fmaf(s1v, W1[k], b1[k]), 0.f);
                c0 = fmaf(h, W2[2 * k], c0);
                c1 = fmaf(h, W2[2 * k + 1], c1);
            }
            q[g2] = (unsigned int)f2bf(c0 * dv) |
                    ((unsigned int)f2bf(c1 * dv) << 16);
        }
    }
}

// ---------------------------------------------------------------------------
// Phase 4: CSR-vector agg2. 16 lanes/node; log_softmax compacted.
// ---------------------------------------------------------------------------
__global__ __launch_bounds__(AGG_T) void k_agg2(
    const unsigned int* __restrict__ file, const int* __restrict__ start,
    const unsigned int* __restrict__ q, const float* __restrict__ dinv,
    const float* __restrict__ b2, float2* __restrict__ out,
    int N, int cap)
{
    __shared__ float s0a[NPBK];
    __shared__ float s1a[NPBK];
    const int t = threadIdx.x;
    const int grp = t >> 4;
    const int sl  = t & (LPN - 1);
    const int g = blockIdx.x * NPBK + grp;

    float a0 = 0.f, a1 = 0.f;
    if (g < N) {
        int b = g >> NPB_SHIFT, loc = g & NPB_MASK;
        const int* st = start + b * (NPB + 1);
        int e0 = st[loc], e1 = st[loc + 1];
        const unsigned int* f = file + (size_t)b * cap;
        for (int j = e0 + sl; j < e1; j += LPN) {
            unsigned int gq = q[__builtin_nontemporal_load(f + j)];
            a0 += bf2f((unsigned short)gq);
            a1 += bf2f((unsigned short)(gq >> 16));
        }
    }
#pragma unroll
    for (int d = LPN / 2; d; d >>= 1) {
        a0 += __shfl_down(a0, d, LPN);
        a1 += __shfl_down(a1, d, LPN);
    }
    if (sl == 0) { s0a[grp] = a0; s1a[grp] = a1; }
    __syncthreads();

    if (t < NPBK) {
        int g2 = blockIdx.x * NPBK + t;
        if (g2 < N) {
            float dv = dinv[g2];
            unsigned int qi = q[g2];
            float o0 = (s0a[t] + bf2f((unsigned short)qi)) * dv + b2[0];
            float o1 = (s1a[t] + bf2f((unsigned short)(qi >> 16))) * dv + b2[1];
            float m = fmaxf(o0, o1);
            float l = m + logf(expf(o0 - m) + expf(o1 - m));
            out[g2] = make_float2(o0 - l, o1 - l);
        }
    }
}

// ===========================================================================
// Fallback path (direct-atomic, fp32) if workspace/shape doesn't fit.
// ===========================================================================
#define NT 256
__global__ __launch_bounds__(NT) void fb_deg(const int* __restrict__ dst,
                                             int* __restrict__ deg, int E) {
    int e = blockIdx.x * blockDim.x + threadIdx.x;
    if (e < E) atomicAdd(&deg[dst[e]], 1);
}
__global__ __launch_bounds__(NT) void fb_node1(const float* __restrict__ x,
                                               const int* __restrict__ deg,
                                               float* __restrict__ dinv,
                                               float* __restrict__ u, int N) {
    int i = blockIdx.x * blockDim.x + threadIdx.x;
    if (i < N) {
        float dv = rsqrtf((float)(deg[i] + 1));
        dinv[i] = dv;
        u[i] = x[i] * dv;
    }
}
__global__ __launch_bounds__(NT) void fb_edge1(const int* __restrict__ src,
                                               const int* __restrict__ dst,
                                               const float* __restrict__ u,
                                               float* __restrict__ agg1, int E) {
    int e = blockIdx.x * blockDim.x + threadIdx.x;
    if (e < E) atomicAdd(&agg1[dst[e]], u[src[e]]);
}
__global__ __launch_bounds__(NT) void fb_node2(const float* __restrict__ agg1,
                                               const float* __restrict__ u,
                                               const float* __restrict__ dinv,
                                               const float* __restrict__ W1,
                                               const float* __restrict__ b1,
                                               const float* __restrict__ W2,
                                               float2* __restrict__ q, int N) {
    int i = blockIdx.x * blockDim.x + threadIdx.x;
    if (i < N) {
        float dv = dinv[i];
        float s1 = (agg1[i] + u[i]) * dv;
        float c0 = 0.f, c1 = 0.f;
#pragma unroll
        for (int k = 0; k < 16; ++k) {
            float h = fmaxf(fmaf(s1, W1[k], b1[k]), 0.f);
            c0 = fmaf(h, W2[2 * k], c0);
            c1 = fmaf(h, W2[2 * k + 1], c1);
        }
        q[i] = make_float2(c0 * dv, c1 * dv);
    }
}
__global__ __launch_bounds__(NT) void fb_edge2(const int* __restrict__ src,
                                               const int* __restrict__ dst,
                                               const float2* __restrict__ q,
                                               float* __restrict__ agg2, int E) {
    int e = blockIdx.x * blockDim.x + threadIdx.x;
    if (e < E) {
        float2 qq = q[src[e]];
        atomicAdd(&agg2[2 * dst[e]], qq.x);
        atomicAdd(&agg2[2 * dst[e] + 1], qq.y);
    }
}
__global__ __launch_bounds__(NT) void fb_node3(const float* __restrict__ agg2,
                                               const float2* __restrict__ q,
                                               const float* __restrict__ dinv,
                                               const float* __restrict__ b2,
                                               float2* __restrict__ out, int N) {
    int i = blockIdx.x * blockDim.x + threadIdx.x;
    if (i < N) {
        float dv = dinv[i];
        float2 qi = q[i];
        float o0 = (agg2[2 * i] + qi.x) * dv + b2[0];
        float o1 = (agg2[2 * i + 1] + qi.y) * dv + b2[1];
        float m = fmaxf(o0, o1);
        float l = m + logf(expf(o0 - m) + expf(o1 - m));
        out[i] = make_float2(o0 - l, o1 - l);
    }
}

// ===========================================================================
extern "C" void kernel_launch(void* const* d_in, const int* in_sizes, int n_in,
                              void* d_out, int out_size, void* d_ws, size_t ws_size,
                              hipStream_t stream) {
    const float* x  = (const float*)d_in[0];
    const int* ei   = (const int*)d_in[1];
    const float* W1 = (const float*)d_in[2];
    const float* b1 = (const float*)d_in[3];
    const float* W2 = (const float*)d_in[4];
    const float* b2 = (const float*)d_in[5];

    const int N = in_sizes[0];
    const int E = in_sizes[1] / 2;
    const int* src = ei;
    const int* dst = ei + E;

    const int nbucket = (N + NPB - 1) / NPB;
    const int cap = ((E / nbucket + 1024) + 63) & ~63;   // must be <= SORT_CAP

    auto align_up = [](size_t v) { return (v + 255) & ~(size_t)255; };
    size_t off_ctr   = 0;
    size_t off_file  = align_up((size_t)MAXB * sizeof(int));
    size_t off_start = align_up(off_file + (size_t)nbucket * SORT_CAP * sizeof(unsigned int));
    size_t off_dinv  = align_up(off_start + (size_t)nbucket * (NPB + 1) * sizeof(int));
    size_t off_u     = align_up(off_dinv + (size_t)N * sizeof(float));
    size_t off_q     = align_up(off_u + (size_t)N * sizeof(unsigned short));
    size_t needed    = off_q + (size_t)N * sizeof(unsigned int);

    char* ws = (char*)d_ws;

    if (nbucket <= MAXB && cap <= SORT_CAP && needed <= ws_size) {
        int*            ctr   = (int*)(ws + off_ctr);
        unsigned int*   file  = (unsigned int*)(ws + off_file);
        int*            start = (int*)(ws + off_start);
        float*          dinv  = (float*)(ws + off_dinv);
        unsigned short* u     = (unsigned short*)(ws + off_u);
        unsigned int*   q     = (unsigned int*)(ws + off_q);

        (void)hipMemsetAsync(ctr, 0, (size_t)MAXB * sizeof(int), stream);

        const int p1Blocks  = (E + CHUNK - 1) / CHUNK;
        const int aggBlocks = (N + NPBK - 1) / NPBK;
        k_bucket<<<p1Blocks, P1T, 0, stream>>>(src, dst, file, ctr, E, nbucket, SORT_CAP);
        k_sort  <<<nbucket, NPB, 0, stream>>>(file, ctr, start, x, dinv, u, N, SORT_CAP);
        k_agg1  <<<aggBlocks, AGG_T, 0, stream>>>(file, start, u, dinv, W1, b1, W2, q, N, SORT_CAP);
        k_agg2  <<<aggBlocks, AGG_T, 0, stream>>>(file, start, q, dinv, b2, (float2*)d_out, N, SORT_CAP);
    } else {
        int*    deg  = (int*)   (ws);
        float*  agg1 = (float*) (ws + (size_t)4 * N);
        float*  agg2 = (float*) (ws + (size_t)8 * N);
        float*  dinv = (float*) (ws + (size_t)16 * N);
        float*  u    = (float*) (ws + (size_t)20 * N);
        float2* q    = (float2*)(ws + (size_t)24 * N);
        (void)hipMemsetAsync(ws, 0, (size_t)16 * N, stream);
        const int nodeBlocks = (N + NT - 1) / NT;
        const int edgeBlocks = (E + NT - 1) / NT;
        fb_deg  <<<edgeBlocks, NT, 0, stream>>>(dst, deg, E);
        fb_node1<<<nodeBlocks, NT, 0, stream>>>(x, deg, dinv, u, N);
        fb_edge1<<<edgeBlocks, NT, 0, stream>>>(src, dst, u, agg1, E);
        fb_node2<<<nodeBlocks, NT, 0, stream>>>(agg1, u, dinv, W1, b1, W2, q, N);
        fb_edge2<<<edgeBlocks, NT, 0, stream>>>(src, dst, q, agg2, E);
        fb_node3<<<nodeBlocks, NT, 0, stream>>>(agg2, q, dinv, b2, (float2*)d_out, N);
    }
}